// Round 12
// baseline (524.958 us; speedup 1.0000x reference)
//
#include <hip/hip_runtime.h>
#include <math.h>

// Problem constants
#define BATCH 128
#define TENC  64
#define NSTEP 63

// Workspace layout (FLOAT offsets)
#define OFF_WA1ET  0         // [256 k][256 j] f32 : W_a1[j][512+k]  (enc part, for enc_proj)
#define OFF_EPT    65536     // [128 b][256 j][64 t] f32
#define OFF_PKH    2162688   // fp16 region (half offsets within):
                             //   PK1: [0,131072)      = [p<4][kk<16][j<256][m<8] = Wa1[j][p*128+kk*8+m]
                             //   PKG: [131072,393216) = [h1<2][kk<16][kh<2][q'<512][m<8]
                             //        = Whh[q][k], q = (q'>>7)*256 + h1*128 + (q'&127), k = kh*128+kk*8+m
#define OFF_ZX     2359296   // [128 b][2 half][256] f32   z-half exchange (single-buffered, chain-safe)
#define OFF_HP     2424832   // [128 b][2 half][128] f32   h-slice exchange
#define OFF_FLAGS  2457600   // [128 b][2 half][2] uint    (monotonic; 0=z-flag, 1=h-flag)

typedef __attribute__((ext_vector_type(8))) _Float16 h8_t;
typedef __attribute__((ext_vector_type(2))) _Float16 h2_t;

#if defined(__has_builtin)
#if __has_builtin(__builtin_amdgcn_fdot2)
#define FDOT2(a, b, c) __builtin_amdgcn_fdot2((a), (b), (c), false)
#endif
#endif
#ifndef FDOT2
#define FDOT2(a, b, c) ((c) + (float)(a)[0] * (float)(b)[0] + (float)(a)[1] * (float)(b)[1])
#endif

__device__ __forceinline__ h2_t h2of(h8_t v, int i) {   // i must be literal (unrolled)
    h2_t r = {v[2 * i], v[2 * i + 1]};
    return r;
}
__device__ __forceinline__ float ftanh(float x) {
    x = fminf(15.f, fmaxf(-15.f, x));
    float e = __expf(2.f * x);
    return (e - 1.f) * __builtin_amdgcn_rcpf(e + 1.f);
}
__device__ __forceinline__ float fsig(float x) {
    return __builtin_amdgcn_rcpf(1.f + __expf(-x));
}

// ---------------------------------------------------------------------------
// Pre-kernel A: pack weights (fp16 stream-ordered) + WA1ET (f32)
// ---------------------------------------------------------------------------
__global__ void pack_weights(const float* __restrict__ Wa1,
                             const float* __restrict__ Whh,
                             float* __restrict__ ws) {
    int idx = blockIdx.x * blockDim.x + threadIdx.x;
    _Float16* PKH = (_Float16*)(ws + OFF_PKH);
    if (idx < 131072) {
        int m = idx & 7, j = (idx >> 3) & 255, kk = (idx >> 11) & 15, p = idx >> 15;
        int k = p * 128 + kk * 8 + m;
        PKH[idx] = (_Float16)Wa1[j * 768 + k];
    } else if (idx < 393216) {
        int n = idx - 131072;
        int m = n & 7, qp = (n >> 3) & 511, kh = (n >> 12) & 1, kk = (n >> 13) & 15, h1 = n >> 17;
        int q = ((qp >> 7) << 8) + h1 * 128 + (qp & 127);
        int k = kh * 128 + kk * 8 + m;
        PKH[131072 + n] = (_Float16)Whh[q * 256 + k];
    } else if (idx < 458752) {
        int n = idx - 393216;
        int k = n >> 8, j = n & 255;
        ws[OFF_WA1ET + n] = Wa1[j * 768 + 512 + k];
    }
}

// Pre-kernel A2: zero the exchange flags (every launch, before decoder)
__global__ void zero_flags(float* __restrict__ ws) {
    unsigned* f = (unsigned*)(ws + OFF_FLAGS);
    f[threadIdx.x] = 0u;   // 512 = [128][2][2]
}

// ---------------------------------------------------------------------------
// Pre-kernel B: EPT[b][j][t] = b_a1[j] + sum_k enc[b][t][k] * W_a1[j][512+k]
// ---------------------------------------------------------------------------
__global__ void enc_proj_kernel(const float* __restrict__ enc,
                                const float* __restrict__ ba1,
                                float* __restrict__ ws) {
    __shared__ float smem[8448];
    const int b  = blockIdx.x >> 1;
    const int th = blockIdx.x & 1;
    const int t0 = th * 32;
    const int tid = threadIdx.x;

    const float* encb = enc + (b * TENC + t0) * 256;
    for (int c = 0; c < 32; ++c) smem[c * 256 + tid] = encb[c * 256 + tid];
    __syncthreads();

    const int w = tid >> 6, l = tid & 63;
    float acc[8][4];
    #pragma unroll
    for (int a = 0; a < 8; ++a)
        #pragma unroll
        for (int c = 0; c < 4; ++c) acc[a][c] = 0.f;

    const float4* WT = (const float4*)(ws + OFF_WA1ET);
    for (int k = 0; k < 256; ++k) {
        float4 wv = WT[k * 64 + l];
        #pragma unroll
        for (int tt = 0; tt < 8; ++tt) {
            float e = smem[(w * 8 + tt) * 256 + k];
            acc[tt][0] += e * wv.x; acc[tt][1] += e * wv.y;
            acc[tt][2] += e * wv.z; acc[tt][3] += e * wv.w;
        }
    }
    float4 bb = ((const float4*)ba1)[l];
    __syncthreads();
    #pragma unroll
    for (int tt = 0; tt < 8; ++tt) {
        smem[(4 * l + 0) * 33 + w * 8 + tt] = acc[tt][0] + bb.x;
        smem[(4 * l + 1) * 33 + w * 8 + tt] = acc[tt][1] + bb.y;
        smem[(4 * l + 2) * 33 + w * 8 + tt] = acc[tt][2] + bb.z;
        smem[(4 * l + 3) * 33 + w * 8 + tt] = acc[tt][3] + bb.w;
    }
    __syncthreads();
    float* EPT = ws + OFF_EPT + b * 16384;
    for (int c = 0; c < 32; ++c) {
        int i = c * 256 + tid;
        int j = i >> 5, t5 = i & 31;
        EPT[j * 64 + t0 + t5] = smem[j * 33 + t5];
    }
}

// ---------------------------------------------------------------------------
// Main kernel: 256 WGs = 2 per batch; WG h1 owns state slice [h1*128, +128).
// Round-10 phase order (P4 full stream covers the z round-trip) plus:
//  - P1 weights PREFETCHED into registers (issued at top of C, used next A)
//  - 64 KB of W_hh (kk 0..4) cached in LDS  -> port traffic 384->320 KB/step
//  - softmax+ytil computed redundantly by waves 0-1 in-register (B6 removed)
// ---------------------------------------------------------------------------
__global__ __launch_bounds__(1024, 4) void decoder_main(
    const float* __restrict__ enc, const float* __restrict__ yhist,
    const float* __restrict__ Wa2,
    const float* __restrict__ Wfc, const float* __restrict__ bfc,
    const float* __restrict__ wih, const float* __restrict__ bih,
    const float* __restrict__ bhh,
    const float* __restrict__ Wff, const float* __restrict__ bff,
    float* __restrict__ ws, float* __restrict__ out) {

    __shared__ float hc[512];        // f32 state: h = [0,256), c = [256,512)
    __shared__ _Float16 hcf16[512] __attribute__((aligned(16)));
    __shared__ float z[256];
    __shared__ float red1[1024];     // P1 partials / scratch
    __shared__ float red2[1024];     // P2 partials [16 j-chunks][64 t]
    __shared__ float g2[1024];       // gate partials [kh<2][q'<512]
    __shared__ float attnw[64];
    __shared__ float encw[64];       // enc[t]·wfcs  (P3-elimination vector)
    __shared__ float wa2s[256];
    __shared__ float ys[64];
    __shared__ h8_t  wc[4096] __attribute__((aligned(16)));  // 64 KB: PKG own-half kk 0..4
    __shared__ float epl[16384];     // EPT[b] : [256 j][64 t]

    const int bid  = blockIdx.x;
    const int b    = bid & 127;
    const int h1   = bid >> 7;       // owned state slice
    const int tid  = threadIdx.x;
    const int lane = tid & 63;
    const int wv   = tid >> 6;

    const _Float16* PKH = (const _Float16*)(ws + OFF_PKH);

    // ---- stage per-batch data into LDS once ----
    const float* EPTb = ws + OFF_EPT + b * 16384;
    const float* encb = enc + b * 16384;
    #pragma unroll
    for (int i = 0; i < 16; ++i) {
        epl[i * 1024 + tid] = EPTb[i * 1024 + tid];
    }
    // W_hh LDS cache: own-half kk 0..4 (64 KB)
    const h8_t* PKGown = (const h8_t*)(PKH + 131072) + h1 * 16384;
    #pragma unroll
    for (int kk = 0; kk < 4; ++kk) wc[kk * 1024 + tid] = PKGown[kk * 1024 + tid];
    if (tid < 512) { hc[tid] = 0.f; hcf16[tid] = (_Float16)0.f; }
    if (tid < 256) wa2s[tid] = Wa2[tid];
    if (tid < NSTEP) ys[tid] = yhist[b * NSTEP + tid];
    const float bfc0  = bfc[0];
    const float wfc_y = Wfc[256];
    // per-thread (tid<128) gate-row constants for the owned slice
    float wii = 0.f, wif = 0.f, wig = 0.f, wio = 0.f;
    float bsi = 0.f, bsf = 0.f, bsg = 0.f, bso = 0.f;
    if (tid < 128) {
        const int q0 = h1 * 128 + tid;
        wii = wih[q0];       bsi = bih[q0]       + bhh[q0];
        wif = wih[256 + q0]; bsf = bih[256 + q0] + bhh[256 + q0];
        wig = wih[512 + q0]; bsg = bih[512 + q0] + bhh[512 + q0];
        wio = wih[768 + q0]; bso = bih[768 + q0] + bhh[768 + q0];
    }
    // encw partials: thread (t = tid>>4, cch = tid&15) covers 16 e-values.
    {
        const int t = tid >> 4, cch = tid & 15;
        float p = 0.f;
        #pragma unroll
        for (int i = 0; i < 16; ++i)
            p += encb[t * 256 + cch * 16 + i] * Wfc[cch * 16 + i];
        red1[t * 16 + cch] = p;
    }
    __syncthreads();
    if (tid < 64) {
        float s = 0.f;
        #pragma unroll
        for (int c = 0; c < 16; ++c) s += red1[tid * 16 + c];
        encw[tid] = s;
    }
    __syncthreads();

    // P1: 4 chunks (c1) of 64 k within the OWNED k-set {h-slice, c-slice}
    const int c1 = tid >> 8, j1 = tid & 255;
    const int p1 = h1 + (c1 & 2);                 // c1 0,1 -> h part; 2,3 -> c part
    const h8_t* W1 = (const h8_t*)PKH + (p1 * 16 + (c1 & 1) * 8) * 256 + j1;
    const _Float16* hp1 = hcf16 + (c1 >> 1) * 256 + h1 * 128 + (c1 & 1) * 64;
    // P4: full-k gate dots; thread = (kh = tid>>9, q' = tid&511)
    const int kh = tid >> 9, qp = tid & 511;
    const h8_t* W4 = PKGown + kh * 512 + qp;
    const _Float16* hgk = hcf16 + kh * 128;

    // P1 weight prefetch registers (8 x h8 = 32 VGPR), loaded in prologue,
    // re-issued at the top of Phase C each step.
    h8_t w1p[8];
    #pragma unroll
    for (int it = 0; it < 8; ++it) w1p[it] = W1[it * 256];

    // exchange buffers / flags
    float* ZXown  = ws + OFF_ZX + (b * 2 + h1) * 256;
    float* ZXpeer = ws + OFF_ZX + (b * 2 + (1 - h1)) * 256;
    float* HPown  = ws + OFF_HP + (b * 2 + h1) * 128;
    float* HPpeer = ws + OFF_HP + (b * 2 + (1 - h1)) * 128;
    unsigned* FLGown  = (unsigned*)(ws + OFF_FLAGS) + (b * 2 + h1) * 2;
    unsigned* FLGpeer = (unsigned*)(ws + OFF_FLAGS) + (b * 2 + (1 - h1)) * 2;

    for (int step = 0; step < NSTEP; ++step) {
        const unsigned tgt = (unsigned)(step + 1);
        // ---- Phase A: P1 dots from prefetched regs (pure VALU, no loads) ----
        {
            float a0 = 0.f, a1 = 0.f;
            #pragma unroll
            for (int it = 0; it < 8; ++it) {
                h8_t hv = *(const h8_t*)(hp1 + it * 8);   // wave-uniform broadcast
                a0 = FDOT2(h2of(w1p[it], 0), h2of(hv, 0), a0);
                a1 = FDOT2(h2of(w1p[it], 1), h2of(hv, 1), a1);
                a0 = FDOT2(h2of(w1p[it], 2), h2of(hv, 2), a0);
                a1 = FDOT2(h2of(w1p[it], 3), h2of(hv, 3), a1);
            }
            red1[c1 * 256 + j1] = a0 + a1;
        }
        // wait for peer h-slice (posted at end of peer's previous step)
        if (tid == 0 && step > 0) {
            while (atomicAdd(&FLGpeer[1], 0u) < (unsigned)step) { __builtin_amdgcn_s_sleep(1); }
        }
        __syncthreads();                                 // B1: red1 ready, peer-h flag seen
        // ---- Phase B: z-own combine+post (tid<256); peer-h read (tid 256..383) ----
        if (tid < 256) {
            float zown = red1[tid] + red1[256 + tid] + red1[512 + tid] + red1[768 + tid];
            z[tid] = zown;
            atomicExch(&ZXown[tid], zown);
        } else if (tid < 384 && step > 0) {
            const int i2 = tid - 256;
            float hp = atomicAdd(&HPpeer[i2], 0.f);
            const int ih = (1 - h1) * 128 + i2;
            hc[ih] = hp; hcf16[ih] = (_Float16)hp;
        }
        __syncthreads();                                 // B2: z posted + peer h in LDS
        if (tid == 0) atomicExch(&FLGown[0], tgt);       // z-flag

        // ---- Phase C: prefetch-issue (next P1) + P4 gate dots.
        //      Port traffic in flight before the z-poll: 128 KB (prefetch)
        //      + 192 KB (kk 4..16 stream) = 320 KB  -> z RTT fully covered.
        float g0 = 0.f, g1 = 0.f;
        {
            #pragma unroll
            for (int it = 0; it < 8; ++it) w1p[it] = W1[it * 256];  // fire-and-forget
            #pragma unroll
            for (int kk = 0; kk < 4; ++kk) {              // cached in LDS
                h8_t w  = wc[kk * 1024 + tid];
                h8_t hv = *(const h8_t*)(hgk + kk * 8);
                g0 = FDOT2(h2of(w, 0), h2of(hv, 0), g0);
                g1 = FDOT2(h2of(w, 1), h2of(hv, 1), g1);
                g0 = FDOT2(h2of(w, 2), h2of(hv, 2), g0);
                g1 = FDOT2(h2of(w, 3), h2of(hv, 3), g1);
            }
            #pragma unroll 4
            for (int kk = 4; kk < 16; ++kk) {             // streamed from L2
                h8_t w  = W4[kk * 1024];
                h8_t hv = *(const h8_t*)(hgk + kk * 8);
                g0 = FDOT2(h2of(w, 0), h2of(hv, 0), g0);
                g1 = FDOT2(h2of(w, 1), h2of(hv, 1), g1);
                g0 = FDOT2(h2of(w, 2), h2of(hv, 2), g0);
                g1 = FDOT2(h2of(w, 3), h2of(hv, 3), g1);
            }
            g2[tid] = g0 + g1;                           // [kh*512 + q']
        }
        if (tid == 0) {
            while (atomicAdd(&FLGpeer[0], 0u) < tgt) { __builtin_amdgcn_s_sleep(1); }
        }
        __syncthreads();                                 // B3: g2 ready + peer z posted
        // ---- Phase D: z full ----
        if (tid < 256) {
            float zp = atomicAdd(&ZXpeer[tid], 0.f);
            z[tid] = z[tid] + zp;                        // commutative -> identical in pair
        }
        __syncthreads();                                 // B4: z ready

        // ---- Phase E: P2 scores partials ----
        {
            float partial = 0.f;
            const int jbase = wv * 16;
            #pragma unroll
            for (int jj = 0; jj < 16; ++jj) {
                const int j = jbase + jj;
                float v = epl[j * 64 + lane] + z[j];
                partial += ftanh(v) * wa2s[j];
            }
            red2[wv * 64 + lane] = partial;
        }
        __syncthreads();                                 // B5: red2 ready
        // ---- Phase F+H: waves 0-1 redundant softmax+ytil, then gate finalize
        //      + state update (tid<128).  No barrier between F and H.
        if (wv < 2) {
            float s = 0.f;
            #pragma unroll
            for (int w2 = 0; w2 < 16; ++w2) s += red2[w2 * 64 + lane];
            float m = s;
            #pragma unroll
            for (int d = 32; d >= 1; d >>= 1) m = fmaxf(m, __shfl_xor(m, d));
            float e = __expf(s - m);
            float su = e;
            #pragma unroll
            for (int d = 32; d >= 1; d >>= 1) su += __shfl_xor(su, d);
            float a = e * __builtin_amdgcn_rcpf(su);
            if (wv == 0) attnw[lane] = a;
            float yp = a * encw[lane];
            #pragma unroll
            for (int d = 32; d >= 1; d >>= 1) yp += __shfl_xor(yp, d);
            const float ytil = yp + wfc_y * ys[step] + bfc0;
            if (tid < 128) {
                float gi = g2[tid]       + g2[512 + tid] + ytil * wii + bsi;
                float gf = g2[128 + tid] + g2[640 + tid] + ytil * wif + bsf;
                float gg = g2[256 + tid] + g2[768 + tid] + ytil * wig + bsg;
                float go = g2[384 + tid] + g2[896 + tid] + ytil * wio + bso;
                const int ih = h1 * 128 + tid;
                float co = hc[256 + ih];
                float cn = fsig(gf) * co + fsig(gi) * ftanh(gg);
                float hn = fsig(go) * ftanh(cn);
                hc[ih] = hn; hc[256 + ih] = cn;
                hcf16[ih] = (_Float16)hn; hcf16[256 + ih] = (_Float16)cn;
                atomicExch(&HPown[tid], hn);             // post own h-slice
            }
        }
        __syncthreads();                                 // B6: state updated, h posted
        if (tid == 0) atomicExch(&FLGown[1], tgt);       // h-flag (consumed next step)
    }

    // ---- final h-exchange so the epilogue sees step-63 peer h ----
    if (tid == 0) {
        while (atomicAdd(&FLGpeer[1], 0u) < (unsigned)NSTEP) { __builtin_amdgcn_s_sleep(1); }
    }
    __syncthreads();
    if (tid < 128) {
        float hp = atomicAdd(&HPpeer[tid], 0.f);
        hc[(1 - h1) * 128 + tid] = hp;
    }
    __syncthreads();

    // ---- epilogue (h1 == 0 only): materialize final ctx from L2, then out ----
    if (h1 == 0) {
        if (tid < 256) {
            float cv = 0.f;
            #pragma unroll 8
            for (int t = 0; t < TENC; ++t)
                cv += attnw[t] * encb[t * 256 + tid];
            red1[tid] = cv;
        }
        __syncthreads();
        if (wv < 2) {
            float partial = 0.f;
            #pragma unroll
            for (int qq = 0; qq < 8; ++qq) {
                const int e2 = qq * 64 + lane;
                float v = (e2 < 256) ? hc[e2] : red1[e2 - 256];
                partial += v * Wff[wv * 512 + e2];
            }
            #pragma unroll
            for (int d = 32; d >= 1; d >>= 1) partial += __shfl_xor(partial, d);
            if (lane == 0) out[b * 2 + wv] = partial + bff[wv];
        }
    }
}

// ---------------------------------------------------------------------------
extern "C" void kernel_launch(void* const* d_in, const int* in_sizes, int n_in,
                              void* d_out, int out_size, void* d_ws, size_t ws_size,
                              hipStream_t stream) {
    const float* enc = (const float*)d_in[0];
    const float* yh  = (const float*)d_in[1];
    const float* Wa1 = (const float*)d_in[2];
    const float* ba1 = (const float*)d_in[3];
    const float* Wa2 = (const float*)d_in[4];
    // d_in[5] = b_a2 : softmax shift-invariant, unused
    const float* Wfc = (const float*)d_in[6];
    const float* bfc = (const float*)d_in[7];
    const float* Wih = (const float*)d_in[8];
    const float* Whh = (const float*)d_in[9];
    const float* bih = (const float*)d_in[10];
    const float* bhh = (const float*)d_in[11];
    const float* Wff = (const float*)d_in[12];
    const float* bff = (const float*)d_in[13];
    float* ws  = (float*)d_ws;
    float* out = (float*)d_out;

    hipLaunchKernelGGL(pack_weights, dim3(1792), dim3(256), 0, stream, Wa1, Whh, ws);
    hipLaunchKernelGGL(zero_flags, dim3(1), dim3(512), 0, stream, ws);
    hipLaunchKernelGGL(enc_proj_kernel, dim3(256), dim3(256), 0, stream, enc, ba1, ws);
    hipLaunchKernelGGL(decoder_main, dim3(256), dim3(1024), 0, stream,
                       enc, yh, Wa2, Wfc, bfc, Wih, bih, bhh, Wff, bff, ws, out);
}

// Round 13
// 424.205 us; speedup vs baseline: 1.2375x; 1.2375x over previous
//
#include <hip/hip_runtime.h>
#include <math.h>

// Problem constants
#define BATCH 128
#define TENC  64
#define NSTEP 63

// Workspace layout (FLOAT offsets)
#define OFF_WA1ET  0         // [256 k][256 j] f32 : W_a1[j][512+k]  (enc part, for enc_proj)
#define OFF_EPT    65536     // [128 b][256 j][64 t] f32
#define OFF_PKH    2162688   // fp16 region (half offsets within):
                             //   PK1n: [0,131072) = [hp<2][kc<8][seg<2][it<4][j7<128][m<8]
                             //         = Wa1[hp*128+j7][k], k = owner(seg,hp) slice, idx256=kc*32+it*8+m
                             //   PKG:  [131072,393216) = [h1<2][kk<16][kh<2][q'<512][m<8]
                             //         = Whh[q][k], q=(q'>>7)*256+h1*128+(q'&127), k=kh*128+kk*8+m
#define OFF_SX     2359296   // [128 b][2 half][64] f32    score-partial exchange
#define OFF_HC     2375680   // [128 b][2 half][256] f32   state exchange (h:0..128, c:128..256)
#define OFF_FLAGS  2441216   // [128 b][2 half][2] uint    (monotonic; 0=state, 1=scores)

typedef __attribute__((ext_vector_type(8))) _Float16 h8_t;
typedef __attribute__((ext_vector_type(2))) _Float16 h2_t;

#if defined(__has_builtin)
#if __has_builtin(__builtin_amdgcn_fdot2)
#define FDOT2(a, b, c) __builtin_amdgcn_fdot2((a), (b), (c), false)
#endif
#endif
#ifndef FDOT2
#define FDOT2(a, b, c) ((c) + (float)(a)[0] * (float)(b)[0] + (float)(a)[1] * (float)(b)[1])
#endif

__device__ __forceinline__ h2_t h2of(h8_t v, int i) {
    h2_t r = {v[2 * i], v[2 * i + 1]};
    return r;
}
__device__ __forceinline__ float ftanh(float x) {
    x = fminf(15.f, fmaxf(-15.f, x));
    float e = __expf(2.f * x);
    return (e - 1.f) * __builtin_amdgcn_rcpf(e + 1.f);
}
__device__ __forceinline__ float fsig(float x) {
    return __builtin_amdgcn_rcpf(1.f + __expf(-x));
}

// ---------------------------------------------------------------------------
// Pre-kernel A: pack weights (fp16 stream-ordered) + WA1ET (f32)
// ---------------------------------------------------------------------------
__global__ void pack_weights(const float* __restrict__ Wa1,
                             const float* __restrict__ Whh,
                             float* __restrict__ ws) {
    int idx = blockIdx.x * blockDim.x + threadIdx.x;
    _Float16* PKH = (_Float16*)(ws + OFF_PKH);
    if (idx < 131072) {
        // PK1n: j-split, full-k, own-k segment first then peer-k segment
        int m = idx & 7, j7 = (idx >> 3) & 127, it = (idx >> 10) & 3;
        int seg = (idx >> 12) & 1, kc = (idx >> 13) & 7, hp = (idx >> 16) & 1;
        int owner = seg ? (1 - hp) : hp;
        int idx256 = kc * 32 + it * 8 + m;              // position within owner's 256-k set
        int k = (idx256 < 128) ? owner * 128 + idx256
                               : 256 + owner * 128 + (idx256 - 128);
        int j = hp * 128 + j7;
        PKH[idx] = (_Float16)Wa1[j * 768 + k];
    } else if (idx < 393216) {
        int n = idx - 131072;
        int m = n & 7, qp = (n >> 3) & 511, kh = (n >> 12) & 1, kk = (n >> 13) & 15, h1 = n >> 17;
        int q = ((qp >> 7) << 8) + h1 * 128 + (qp & 127);
        int k = kh * 128 + kk * 8 + m;
        PKH[131072 + n] = (_Float16)Whh[q * 256 + k];
    } else if (idx < 458752) {
        int n = idx - 393216;
        int k = n >> 8, j = n & 255;
        ws[OFF_WA1ET + n] = Wa1[j * 768 + 512 + k];
    }
}

// Pre-kernel A2: zero the exchange flags (every launch, before decoder)
__global__ void zero_flags(float* __restrict__ ws) {
    unsigned* f = (unsigned*)(ws + OFF_FLAGS);
    f[threadIdx.x] = 0u;   // 512 = [128][2][2]
}

// ---------------------------------------------------------------------------
// Pre-kernel B: EPT[b][j][t] = b_a1[j] + sum_k enc[b][t][k] * W_a1[j][512+k]
// ---------------------------------------------------------------------------
__global__ void enc_proj_kernel(const float* __restrict__ enc,
                                const float* __restrict__ ba1,
                                float* __restrict__ ws) {
    __shared__ float smem[8448];
    const int b  = blockIdx.x >> 1;
    const int th = blockIdx.x & 1;
    const int t0 = th * 32;
    const int tid = threadIdx.x;

    const float* encb = enc + (b * TENC + t0) * 256;
    for (int c = 0; c < 32; ++c) smem[c * 256 + tid] = encb[c * 256 + tid];
    __syncthreads();

    const int w = tid >> 6, l = tid & 63;
    float acc[8][4];
    #pragma unroll
    for (int a = 0; a < 8; ++a)
        #pragma unroll
        for (int c = 0; c < 4; ++c) acc[a][c] = 0.f;

    const float4* WT = (const float4*)(ws + OFF_WA1ET);
    for (int k = 0; k < 256; ++k) {
        float4 wv = WT[k * 64 + l];
        #pragma unroll
        for (int tt = 0; tt < 8; ++tt) {
            float e = smem[(w * 8 + tt) * 256 + k];
            acc[tt][0] += e * wv.x; acc[tt][1] += e * wv.y;
            acc[tt][2] += e * wv.z; acc[tt][3] += e * wv.w;
        }
    }
    float4 bb = ((const float4*)ba1)[l];
    __syncthreads();
    #pragma unroll
    for (int tt = 0; tt < 8; ++tt) {
        smem[(4 * l + 0) * 33 + w * 8 + tt] = acc[tt][0] + bb.x;
        smem[(4 * l + 1) * 33 + w * 8 + tt] = acc[tt][1] + bb.y;
        smem[(4 * l + 2) * 33 + w * 8 + tt] = acc[tt][2] + bb.z;
        smem[(4 * l + 3) * 33 + w * 8 + tt] = acc[tt][3] + bb.w;
    }
    __syncthreads();
    float* EPT = ws + OFF_EPT + b * 16384;
    for (int c = 0; c < 32; ++c) {
        int i = c * 256 + tid;
        int j = i >> 5, t5 = i & 31;
        EPT[j * 64 + t0 + t5] = smem[j * 33 + t5];
    }
}

// ---------------------------------------------------------------------------
// Main kernel: 256 WGs = 2 per batch. WG h1 owns state slice [h1*128,+128)
// AND attention j-half [h1*128,+128). z is computed full-k locally (no z
// exchange); the mid-step exchange is 64 score-partials (hidden under the P4
// stream); the state (h,c) exchange rides the step boundary (hidden under the
// own-k half of P1). All pair-combining sums are 2-operand commutative.
// ---------------------------------------------------------------------------
__global__ __launch_bounds__(1024, 4) void decoder_main(
    const float* __restrict__ enc, const float* __restrict__ yhist,
    const float* __restrict__ Wa2,
    const float* __restrict__ Wfc, const float* __restrict__ bfc,
    const float* __restrict__ wih, const float* __restrict__ bih,
    const float* __restrict__ bhh,
    const float* __restrict__ Wff, const float* __restrict__ bff,
    float* __restrict__ ws, float* __restrict__ out) {

    __shared__ float hc[512];        // f32 state: h = [0,256), c = [256,512)
    __shared__ _Float16 hcf16[512] __attribute__((aligned(16)));
    __shared__ float z[128];         // own j-half, full-k
    __shared__ float red1[1024];     // P1 partials [kc<8][j7<128] / scratch
    __shared__ float red2[1024];     // score partials [jc<16][t<64]
    __shared__ float g2[1024];       // gate partials [kh<2][q'<512]
    __shared__ float attnw[64];
    __shared__ float encw[64];
    __shared__ float sownl[64];      // own score-partials (saved for D)
    __shared__ float wa2s[128];      // own j-half of W_a2
    __shared__ float ys[64];
    __shared__ float ytil_s;
    __shared__ h8_t  wc[4096] __attribute__((aligned(16)));  // 64 KB W_hh kk 0..4
    __shared__ float epl[8192];      // EPT own j-half : [128 j'][64 t]

    const int bid  = blockIdx.x;
    const int b    = bid & 127;
    const int h1   = bid >> 7;
    const int tid  = threadIdx.x;
    const int lane = tid & 63;
    const int wv   = tid >> 6;

    const _Float16* PKH = (const _Float16*)(ws + OFF_PKH);

    // ---- stage per-batch data into LDS once ----
    const float* EPTb = ws + OFF_EPT + b * 16384 + h1 * 8192;
    const float* encb = enc + b * 16384;
    #pragma unroll
    for (int i = 0; i < 8; ++i) epl[i * 1024 + tid] = EPTb[i * 1024 + tid];
    const h8_t* PKGown = (const h8_t*)(PKH + 131072) + h1 * 16384;
    #pragma unroll
    for (int kk = 0; kk < 4; ++kk) wc[kk * 1024 + tid] = PKGown[kk * 1024 + tid];
    if (tid < 512) { hc[tid] = 0.f; hcf16[tid] = (_Float16)0.f; }
    if (tid < 128) wa2s[tid] = Wa2[h1 * 128 + tid];
    if (tid < NSTEP) ys[tid] = yhist[b * NSTEP + tid];
    const float bfc0  = bfc[0];
    const float wfc_y = Wfc[256];
    float wii = 0.f, wif = 0.f, wig = 0.f, wio = 0.f;
    float bsi = 0.f, bsf = 0.f, bsg = 0.f, bso = 0.f;
    if (tid < 128) {
        const int q0 = h1 * 128 + tid;
        wii = wih[q0];       bsi = bih[q0]       + bhh[q0];
        wif = wih[256 + q0]; bsf = bih[256 + q0] + bhh[256 + q0];
        wig = wih[512 + q0]; bsg = bih[512 + q0] + bhh[512 + q0];
        wio = wih[768 + q0]; bso = bih[768 + q0] + bhh[768 + q0];
    }
    {   // encw[t] = enc[t]·Wfc[0:256]
        const int t = tid >> 4, cch = tid & 15;
        float p = 0.f;
        #pragma unroll
        for (int i = 0; i < 16; ++i)
            p += encb[t * 256 + cch * 16 + i] * Wfc[cch * 16 + i];
        red1[t * 16 + cch] = p;
    }
    __syncthreads();
    if (tid < 64) {
        float s = 0.f;
        #pragma unroll
        for (int c = 0; c < 16; ++c) s += red1[tid * 16 + c];
        encw[tid] = s;
    }
    __syncthreads();

    // P1 thread mapping: j7 = tid&127, kc = tid>>7 (8 chunks x 64 k; 32 own + 32 peer)
    const int kc = tid >> 7, j7 = tid & 127;
    const h8_t* W1 = (const h8_t*)PKH + h1 * 8192 + kc * 1024 + j7;
    const _Float16* hb_own  = hcf16 + ((kc < 4) ? h1 * 128 + kc * 32
                                                : 256 + h1 * 128 + (kc - 4) * 32);
    const _Float16* hb_peer = hcf16 + ((kc < 4) ? (1 - h1) * 128 + kc * 32
                                                : 256 + (1 - h1) * 128 + (kc - 4) * 32);
    // P4 mapping
    const int kh = tid >> 9, qp = tid & 511;
    const h8_t* W4 = PKGown + kh * 512 + qp;
    const _Float16* hgk = hcf16 + kh * 128;

    // exchange buffers / flags
    float* SXown  = ws + OFF_SX + (b * 2 + h1) * 64;
    float* SXpeer = ws + OFF_SX + (b * 2 + (1 - h1)) * 64;
    float* HCown  = ws + OFF_HC + (b * 2 + h1) * 256;
    float* HCpeer = ws + OFF_HC + (b * 2 + (1 - h1)) * 256;
    unsigned* FLGown  = (unsigned*)(ws + OFF_FLAGS) + (b * 2 + h1) * 2;
    unsigned* FLGpeer = (unsigned*)(ws + OFF_FLAGS) + (b * 2 + (1 - h1)) * 2;

    for (int step = 0; step < NSTEP; ++step) {
        const unsigned tgt = (unsigned)(step + 1);
        float a0 = 0.f, a1 = 0.f;
        // ---- A1: own-k segment (64 KB stream; covers peer-state arrival) ----
        #pragma unroll
        for (int it = 0; it < 4; ++it) {
            h8_t w  = W1[it * 128];
            h8_t hv = *(const h8_t*)(hb_own + it * 8);
            a0 = FDOT2(h2of(w, 0), h2of(hv, 0), a0);
            a1 = FDOT2(h2of(w, 1), h2of(hv, 1), a1);
            a0 = FDOT2(h2of(w, 2), h2of(hv, 2), a0);
            a1 = FDOT2(h2of(w, 3), h2of(hv, 3), a1);
        }
        if (tid == 0 && step > 0) {
            while (atomicAdd(&FLGpeer[0], 0u) < (unsigned)step) { __builtin_amdgcn_s_sleep(1); }
        }
        __syncthreads();                                 // B0: peer-state flag seen
        if (tid < 256 && step > 0) {                     // read peer h,c into LDS
            float v = atomicAdd(&HCpeer[tid], 0.f);
            const int ih = (tid < 128) ? (1 - h1) * 128 + tid
                                       : 256 + (1 - h1) * 128 + (tid - 128);
            hc[ih] = v; hcf16[ih] = (_Float16)v;
        }
        __syncthreads();                                 // B0': peer state in LDS
        // ---- A2: peer-k segment ----
        #pragma unroll
        for (int it = 0; it < 4; ++it) {
            h8_t w  = W1[512 + it * 128];
            h8_t hv = *(const h8_t*)(hb_peer + it * 8);
            a0 = FDOT2(h2of(w, 0), h2of(hv, 0), a0);
            a1 = FDOT2(h2of(w, 1), h2of(hv, 1), a1);
            a0 = FDOT2(h2of(w, 2), h2of(hv, 2), a0);
            a1 = FDOT2(h2of(w, 3), h2of(hv, 3), a1);
        }
        red1[kc * 128 + j7] = a0 + a1;
        __syncthreads();                                 // B1: red1 ready
        if (tid < 128) {                                 // z full-k for own j-half
            float s = red1[tid];
            #pragma unroll
            for (int c = 1; c < 8; ++c) s += red1[c * 128 + tid];
            z[tid] = s;
        }
        __syncthreads();                                 // B2: z ready

        // ---- C: score partials over own j-half (8 tanh/thread) ----
        {
            const int jc = tid >> 6;
            float partial = 0.f;
            #pragma unroll
            for (int jj = 0; jj < 8; ++jj) {
                const int j = jc * 8 + jj;
                float v = epl[j * 64 + lane] + z[j];
                partial += ftanh(v) * wa2s[j];
            }
            red2[jc * 64 + lane] = partial;
        }
        __syncthreads();                                 // B3: red2 ready

        // ---- C2: wave0 posts score-partials; all waves run P4 (hides RTT) ----
        if (wv == 0) {
            float s = 0.f;
            #pragma unroll
            for (int w2 = 0; w2 < 16; ++w2) s += red2[w2 * 64 + lane];
            sownl[lane] = s;
            atomicExch(&SXown[lane], s);
            asm volatile("s_waitcnt vmcnt(0)" ::: "memory");
            if (lane == 0) atomicExch(&FLGown[1], tgt);  // score flag
        }
        float g0 = 0.f, g1 = 0.f;
        #pragma unroll
        for (int kk = 0; kk < 4; ++kk) {                 // cached in LDS
            h8_t w  = wc[kk * 1024 + tid];
            h8_t hv = *(const h8_t*)(hgk + kk * 8);
            g0 = FDOT2(h2of(w, 0), h2of(hv, 0), g0);
            g1 = FDOT2(h2of(w, 1), h2of(hv, 1), g1);
            g0 = FDOT2(h2of(w, 2), h2of(hv, 2), g0);
            g1 = FDOT2(h2of(w, 3), h2of(hv, 3), g1);
        }
        #pragma unroll 4
        for (int kk = 4; kk < 16; ++kk) {                // streamed from L2 (192 KB)
            h8_t w  = W4[kk * 1024];
            h8_t hv = *(const h8_t*)(hgk + kk * 8);
            g0 = FDOT2(h2of(w, 0), h2of(hv, 0), g0);
            g1 = FDOT2(h2of(w, 1), h2of(hv, 1), g1);
            g0 = FDOT2(h2of(w, 2), h2of(hv, 2), g0);
            g1 = FDOT2(h2of(w, 3), h2of(hv, 3), g1);
        }
        g2[tid] = g0 + g1;
        if (tid == 0) {
            while (atomicAdd(&FLGpeer[1], 0u) < tgt) { __builtin_amdgcn_s_sleep(1); }
        }
        __syncthreads();                                 // B4: g2 ready + peer scores posted

        // ---- D: wave0 reads peer scores, softmax + ytil ----
        if (wv == 0) {
            float sp = atomicAdd(&SXpeer[lane], 0.f);
            float s  = sownl[lane] + sp;                 // commutative pair sum
            float m = s;
            #pragma unroll
            for (int d = 32; d >= 1; d >>= 1) m = fmaxf(m, __shfl_xor(m, d));
            float e = __expf(s - m);
            float su = e;
            #pragma unroll
            for (int d = 32; d >= 1; d >>= 1) su += __shfl_xor(su, d);
            float a = e * __builtin_amdgcn_rcpf(su);
            attnw[lane] = a;
            float yp = a * encw[lane];
            #pragma unroll
            for (int d = 32; d >= 1; d >>= 1) yp += __shfl_xor(yp, d);
            if (lane == 0) ytil_s = yp + wfc_y * ys[step] + bfc0;
        }
        __syncthreads();                                 // B5: ytil ready

        // ---- H: gates finalize + own-slice state update + post h,c ----
        if (tid < 128) {
            const float ytil = ytil_s;
            float gi = g2[tid]       + g2[512 + tid] + ytil * wii + bsi;
            float gf = g2[128 + tid] + g2[640 + tid] + ytil * wif + bsf;
            float gg = g2[256 + tid] + g2[768 + tid] + ytil * wig + bsg;
            float go = g2[384 + tid] + g2[896 + tid] + ytil * wio + bso;
            const int ih = h1 * 128 + tid;
            float co = hc[256 + ih];
            float cn = fsig(gf) * co + fsig(gi) * ftanh(gg);
            float hn = fsig(go) * ftanh(cn);
            hc[ih] = hn; hc[256 + ih] = cn;
            hcf16[ih] = (_Float16)hn; hcf16[256 + ih] = (_Float16)cn;
            atomicExch(&HCown[tid], hn);
            atomicExch(&HCown[128 + tid], cn);
        }
        __syncthreads();                                 // B6: updated + posts drained
        if (tid == 0) atomicExch(&FLGown[0], tgt);       // state flag
    }

    // ---- final: read peer h for the epilogue ----
    if (tid == 0) {
        while (atomicAdd(&FLGpeer[0], 0u) < (unsigned)NSTEP) { __builtin_amdgcn_s_sleep(1); }
    }
    __syncthreads();
    if (tid < 128) {
        hc[(1 - h1) * 128 + tid] = atomicAdd(&HCpeer[tid], 0.f);
    }
    __syncthreads();

    // ---- epilogue (h1 == 0 only): final ctx from attnw, then out ----
    if (h1 == 0) {
        if (tid < 256) {
            float cv = 0.f;
            #pragma unroll 8
            for (int t = 0; t < TENC; ++t)
                cv += attnw[t] * encb[t * 256 + tid];
            red1[tid] = cv;
        }
        __syncthreads();
        if (wv < 2) {
            float partial = 0.f;
            #pragma unroll
            for (int qq = 0; qq < 8; ++qq) {
                const int e2 = qq * 64 + lane;
                float v = (e2 < 256) ? hc[e2] : red1[e2 - 256];
                partial += v * Wff[wv * 512 + e2];
            }
            #pragma unroll
            for (int d = 32; d >= 1; d >>= 1) partial += __shfl_xor(partial, d);
            if (lane == 0) out[b * 2 + wv] = partial + bff[wv];
        }
    }
}

// ---------------------------------------------------------------------------
extern "C" void kernel_launch(void* const* d_in, const int* in_sizes, int n_in,
                              void* d_out, int out_size, void* d_ws, size_t ws_size,
                              hipStream_t stream) {
    const float* enc = (const float*)d_in[0];
    const float* yh  = (const float*)d_in[1];
    const float* Wa1 = (const float*)d_in[2];
    const float* ba1 = (const float*)d_in[3];
    const float* Wa2 = (const float*)d_in[4];
    // d_in[5] = b_a2 : softmax shift-invariant, unused
    const float* Wfc = (const float*)d_in[6];
    const float* bfc = (const float*)d_in[7];
    const float* Wih = (const float*)d_in[8];
    const float* Whh = (const float*)d_in[9];
    const float* bih = (const float*)d_in[10];
    const float* bhh = (const float*)d_in[11];
    const float* Wff = (const float*)d_in[12];
    const float* bff = (const float*)d_in[13];
    float* ws  = (float*)d_ws;
    float* out = (float*)d_out;

    hipLaunchKernelGGL(pack_weights, dim3(1792), dim3(256), 0, stream, Wa1, Whh, ws);
    hipLaunchKernelGGL(zero_flags, dim3(1), dim3(512), 0, stream, ws);
    hipLaunchKernelGGL(enc_proj_kernel, dim3(256), dim3(256), 0, stream, enc, ba1, ws);
    hipLaunchKernelGGL(decoder_main, dim3(256), dim3(1024), 0, stream,
                       enc, yh, Wa2, Wfc, bfc, Wih, bih, bhh, Wff, bff, ws, out);
}

// Round 14
// 408.450 us; speedup vs baseline: 1.2852x; 1.0386x over previous
//
#include <hip/hip_runtime.h>
#include <math.h>

// Problem constants
#define BATCH 128
#define TENC  64
#define NSTEP 63

// Workspace layout (FLOAT offsets)
#define OFF_WA1ET  0         // [256 k][256 j] f32 : W_a1[j][512+k]  (enc part, for enc_proj)
#define OFF_EPT    65536     // [128 b][256 j][64 t] f32
#define OFF_PKH    2162688   // fp16 region (half offsets within):
                             //   PK1n: [0,131072) = [hp<2][kc<8][seg<2][it<4][j7<128][m<8]
                             //         = Wa1[hp*128+j7][k], k = owner(seg,hp) slice, idx256=kc*32+it*8+m
                             //   PKG:  [131072,393216) = [h1<2][kk<16][kh<2][q'<512][m<8]
                             //         = Whh[q][k], q=(q'>>7)*256+h1*128+(q'&127), k=kh*128+kk*8+m
#define OFF_SX     2359296   // [128 b][2 half][64] f32    score-partial exchange
#define OFF_HX     2375680   // [128 b][2 half][128] u32   packed state exchange {h:f16 lo, c:f16 hi}
#define OFF_FLAGS  2408448   // [128 b][2 half][2] uint    (monotonic; 0=state, 1=scores)

typedef __attribute__((ext_vector_type(8))) _Float16 h8_t;
typedef __attribute__((ext_vector_type(2))) _Float16 h2_t;

#if defined(__has_builtin)
#if __has_builtin(__builtin_amdgcn_fdot2)
#define FDOT2(a, b, c) __builtin_amdgcn_fdot2((a), (b), (c), false)
#endif
#endif
#ifndef FDOT2
#define FDOT2(a, b, c) ((c) + (float)(a)[0] * (float)(b)[0] + (float)(a)[1] * (float)(b)[1])
#endif

__device__ __forceinline__ h2_t h2of(h8_t v, int i) {
    h2_t r = {v[2 * i], v[2 * i + 1]};
    return r;
}
__device__ __forceinline__ float ftanh(float x) {
    x = fminf(15.f, fmaxf(-15.f, x));
    float e = __expf(2.f * x);
    return (e - 1.f) * __builtin_amdgcn_rcpf(e + 1.f);
}
__device__ __forceinline__ float fsig(float x) {
    return __builtin_amdgcn_rcpf(1.f + __expf(-x));
}
__device__ __forceinline__ unsigned pack_hc(float h, float c) {
    unsigned short hu = __builtin_bit_cast(unsigned short, (_Float16)h);
    unsigned short cu = __builtin_bit_cast(unsigned short, (_Float16)c);
    return (unsigned)hu | ((unsigned)cu << 16);
}

// ---------------------------------------------------------------------------
// Pre-kernel A: pack weights (fp16 stream-ordered) + WA1ET (f32)
// ---------------------------------------------------------------------------
__global__ void pack_weights(const float* __restrict__ Wa1,
                             const float* __restrict__ Whh,
                             float* __restrict__ ws) {
    int idx = blockIdx.x * blockDim.x + threadIdx.x;
    _Float16* PKH = (_Float16*)(ws + OFF_PKH);
    if (idx < 131072) {
        // PK1n: j-split, full-k, own-k segment first then peer-k segment
        int m = idx & 7, j7 = (idx >> 3) & 127, it = (idx >> 10) & 3;
        int seg = (idx >> 12) & 1, kc = (idx >> 13) & 7, hp = (idx >> 16) & 1;
        int owner = seg ? (1 - hp) : hp;
        int idx256 = kc * 32 + it * 8 + m;
        int k = (idx256 < 128) ? owner * 128 + idx256
                               : 256 + owner * 128 + (idx256 - 128);
        int j = hp * 128 + j7;
        PKH[idx] = (_Float16)Wa1[j * 768 + k];
    } else if (idx < 393216) {
        int n = idx - 131072;
        int m = n & 7, qp = (n >> 3) & 511, kh = (n >> 12) & 1, kk = (n >> 13) & 15, h1 = n >> 17;
        int q = ((qp >> 7) << 8) + h1 * 128 + (qp & 127);
        int k = kh * 128 + kk * 8 + m;
        PKH[131072 + n] = (_Float16)Whh[q * 256 + k];
    } else if (idx < 458752) {
        int n = idx - 393216;
        int k = n >> 8, j = n & 255;
        ws[OFF_WA1ET + n] = Wa1[j * 768 + 512 + k];
    }
}

// Pre-kernel A2: zero the exchange flags (every launch, before decoder)
__global__ void zero_flags(float* __restrict__ ws) {
    unsigned* f = (unsigned*)(ws + OFF_FLAGS);
    f[threadIdx.x] = 0u;   // 512 = [128][2][2]
}

// ---------------------------------------------------------------------------
// Pre-kernel B: EPT[b][j][t] = b_a1[j] + sum_k enc[b][t][k] * W_a1[j][512+k]
// ---------------------------------------------------------------------------
__global__ void enc_proj_kernel(const float* __restrict__ enc,
                                const float* __restrict__ ba1,
                                float* __restrict__ ws) {
    __shared__ float smem[8448];
    const int b  = blockIdx.x >> 1;
    const int th = blockIdx.x & 1;
    const int t0 = th * 32;
    const int tid = threadIdx.x;

    const float* encb = enc + (b * TENC + t0) * 256;
    for (int c = 0; c < 32; ++c) smem[c * 256 + tid] = encb[c * 256 + tid];
    __syncthreads();

    const int w = tid >> 6, l = tid & 63;
    float acc[8][4];
    #pragma unroll
    for (int a = 0; a < 8; ++a)
        #pragma unroll
        for (int c = 0; c < 4; ++c) acc[a][c] = 0.f;

    const float4* WT = (const float4*)(ws + OFF_WA1ET);
    for (int k = 0; k < 256; ++k) {
        float4 wv = WT[k * 64 + l];
        #pragma unroll
        for (int tt = 0; tt < 8; ++tt) {
            float e = smem[(w * 8 + tt) * 256 + k];
            acc[tt][0] += e * wv.x; acc[tt][1] += e * wv.y;
            acc[tt][2] += e * wv.z; acc[tt][3] += e * wv.w;
        }
    }
    float4 bb = ((const float4*)ba1)[l];
    __syncthreads();
    #pragma unroll
    for (int tt = 0; tt < 8; ++tt) {
        smem[(4 * l + 0) * 33 + w * 8 + tt] = acc[tt][0] + bb.x;
        smem[(4 * l + 1) * 33 + w * 8 + tt] = acc[tt][1] + bb.y;
        smem[(4 * l + 2) * 33 + w * 8 + tt] = acc[tt][2] + bb.z;
        smem[(4 * l + 3) * 33 + w * 8 + tt] = acc[tt][3] + bb.w;
    }
    __syncthreads();
    float* EPT = ws + OFF_EPT + b * 16384;
    for (int c = 0; c < 32; ++c) {
        int i = c * 256 + tid;
        int j = i >> 5, t5 = i & 31;
        EPT[j * 64 + t0 + t5] = smem[j * 33 + t5];
    }
}

// ---------------------------------------------------------------------------
// Main kernel: 256 WGs = 2 per batch. WG h1 owns state slice [h1*128,+128)
// AND attention j-half [h1*128,+128). Round-13 structure plus:
//  - state exchange packed to u32 {h:f16, c:f16} (peer state is only ever
//    consumed as f16) -> 128 posts/reads instead of 256
//  - W_hh LDS cache 4->6 kk chunks (96 KB): port 320->288 KB/step
//  - softmax+ytil fused into H (tid<128 redundant, in-register) -> B5 removed
// ---------------------------------------------------------------------------
__global__ __launch_bounds__(1024, 4) void decoder_main(
    const float* __restrict__ enc, const float* __restrict__ yhist,
    const float* __restrict__ Wa2,
    const float* __restrict__ Wfc, const float* __restrict__ bfc,
    const float* __restrict__ wih, const float* __restrict__ bih,
    const float* __restrict__ bhh,
    const float* __restrict__ Wff, const float* __restrict__ bff,
    float* __restrict__ ws, float* __restrict__ out) {

    __shared__ float hc[512];        // f32 state: h = [0,256), c = [256,512)
    __shared__ _Float16 hcf16[512] __attribute__((aligned(16)));
    __shared__ float z[128];
    __shared__ float red1[1024];
    __shared__ float red2[1024];
    __shared__ float g2[1024];
    __shared__ float attnw[64];
    __shared__ float encw[64];
    __shared__ float sownl[64];
    __shared__ float wa2s[128];
    __shared__ float ys[64];
    __shared__ h8_t  wc[6144] __attribute__((aligned(16)));  // 96 KB W_hh kk 0..6
    __shared__ float epl[8192];      // EPT own j-half : [128 j'][64 t]

    const int bid  = blockIdx.x;
    const int b    = bid & 127;
    const int h1   = bid >> 7;
    const int tid  = threadIdx.x;
    const int lane = tid & 63;
    const int wv   = tid >> 6;

    const _Float16* PKH = (const _Float16*)(ws + OFF_PKH);

    // ---- stage per-batch data into LDS once ----
    const float* EPTb = ws + OFF_EPT + b * 16384 + h1 * 8192;
    const float* encb = enc + b * 16384;
    #pragma unroll
    for (int i = 0; i < 8; ++i) epl[i * 1024 + tid] = EPTb[i * 1024 + tid];
    const h8_t* PKGown = (const h8_t*)(PKH + 131072) + h1 * 16384;
    #pragma unroll
    for (int kk = 0; kk < 6; ++kk) wc[kk * 1024 + tid] = PKGown[kk * 1024 + tid];
    if (tid < 512) { hc[tid] = 0.f; hcf16[tid] = (_Float16)0.f; }
    if (tid < 128) wa2s[tid] = Wa2[h1 * 128 + tid];
    if (tid < NSTEP) ys[tid] = yhist[b * NSTEP + tid];
    const float bfc0  = bfc[0];
    const float wfc_y = Wfc[256];
    float wii = 0.f, wif = 0.f, wig = 0.f, wio = 0.f;
    float bsi = 0.f, bsf = 0.f, bsg = 0.f, bso = 0.f;
    if (tid < 128) {
        const int q0 = h1 * 128 + tid;
        wii = wih[q0];       bsi = bih[q0]       + bhh[q0];
        wif = wih[256 + q0]; bsf = bih[256 + q0] + bhh[256 + q0];
        wig = wih[512 + q0]; bsg = bih[512 + q0] + bhh[512 + q0];
        wio = wih[768 + q0]; bso = bih[768 + q0] + bhh[768 + q0];
    }
    {   // encw[t] = enc[t]·Wfc[0:256]
        const int t = tid >> 4, cch = tid & 15;
        float p = 0.f;
        #pragma unroll
        for (int i = 0; i < 16; ++i)
            p += encb[t * 256 + cch * 16 + i] * Wfc[cch * 16 + i];
        red1[t * 16 + cch] = p;
    }
    __syncthreads();
    if (tid < 64) {
        float s = 0.f;
        #pragma unroll
        for (int c = 0; c < 16; ++c) s += red1[tid * 16 + c];
        encw[tid] = s;
    }
    __syncthreads();

    // P1 thread mapping: j7 = tid&127, kc = tid>>7
    const int kc = tid >> 7, j7 = tid & 127;
    const h8_t* W1 = (const h8_t*)PKH + h1 * 8192 + kc * 1024 + j7;
    const _Float16* hb_own  = hcf16 + ((kc < 4) ? h1 * 128 + kc * 32
                                                : 256 + h1 * 128 + (kc - 4) * 32);
    const _Float16* hb_peer = hcf16 + ((kc < 4) ? (1 - h1) * 128 + kc * 32
                                                : 256 + (1 - h1) * 128 + (kc - 4) * 32);
    // P4 mapping
    const int kh = tid >> 9, qp = tid & 511;
    const h8_t* W4 = PKGown + kh * 512 + qp;
    const _Float16* hgk = hcf16 + kh * 128;

    // exchange buffers / flags
    float*    SXown  = ws + OFF_SX + (b * 2 + h1) * 64;
    float*    SXpeer = ws + OFF_SX + (b * 2 + (1 - h1)) * 64;
    unsigned* HXown  = (unsigned*)(ws + OFF_HX) + (b * 2 + h1) * 128;
    unsigned* HXpeer = (unsigned*)(ws + OFF_HX) + (b * 2 + (1 - h1)) * 128;
    unsigned* FLGown  = (unsigned*)(ws + OFF_FLAGS) + (b * 2 + h1) * 2;
    unsigned* FLGpeer = (unsigned*)(ws + OFF_FLAGS) + (b * 2 + (1 - h1)) * 2;

    for (int step = 0; step < NSTEP; ++step) {
        const unsigned tgt = (unsigned)(step + 1);
        float a0 = 0.f, a1 = 0.f;
        // ---- A1: own-k segment (64 KB stream; covers peer-state arrival) ----
        #pragma unroll
        for (int it = 0; it < 4; ++it) {
            h8_t w  = W1[it * 128];
            h8_t hv = *(const h8_t*)(hb_own + it * 8);
            a0 = FDOT2(h2of(w, 0), h2of(hv, 0), a0);
            a1 = FDOT2(h2of(w, 1), h2of(hv, 1), a1);
            a0 = FDOT2(h2of(w, 2), h2of(hv, 2), a0);
            a1 = FDOT2(h2of(w, 3), h2of(hv, 3), a1);
        }
        if (tid == 0 && step > 0) {
            while (atomicAdd(&FLGpeer[0], 0u) < (unsigned)step) { __builtin_amdgcn_s_sleep(1); }
        }
        __syncthreads();                                 // B0: peer-state flag seen
        if (tid < 128 && step > 0) {                     // packed peer state -> LDS
            unsigned u = atomicAdd(&HXpeer[tid], 0u);
            _Float16 hv16 = __builtin_bit_cast(_Float16, (unsigned short)(u & 0xffffu));
            _Float16 cv16 = __builtin_bit_cast(_Float16, (unsigned short)(u >> 16));
            const int ih = (1 - h1) * 128 + tid;
            hcf16[ih] = hv16; hcf16[256 + ih] = cv16;
            hc[ih] = (float)hv16;                        // epilogue-only f32 copy
        }
        __syncthreads();                                 // B0': peer state in LDS
        // ---- A2: peer-k segment ----
        #pragma unroll
        for (int it = 0; it < 4; ++it) {
            h8_t w  = W1[512 + it * 128];
            h8_t hv = *(const h8_t*)(hb_peer + it * 8);
            a0 = FDOT2(h2of(w, 0), h2of(hv, 0), a0);
            a1 = FDOT2(h2of(w, 1), h2of(hv, 1), a1);
            a0 = FDOT2(h2of(w, 2), h2of(hv, 2), a0);
            a1 = FDOT2(h2of(w, 3), h2of(hv, 3), a1);
        }
        red1[kc * 128 + j7] = a0 + a1;
        __syncthreads();                                 // B1: red1 ready
        if (tid < 128) {                                 // z full-k for own j-half
            float s = red1[tid];
            #pragma unroll
            for (int c = 1; c < 8; ++c) s += red1[c * 128 + tid];
            z[tid] = s;
        }
        __syncthreads();                                 // B2: z ready

        // ---- C: score partials over own j-half (8 tanh/thread) ----
        {
            const int jc = tid >> 6;
            float partial = 0.f;
            #pragma unroll
            for (int jj = 0; jj < 8; ++jj) {
                const int j = jc * 8 + jj;
                float v = epl[j * 64 + lane] + z[j];
                partial += ftanh(v) * wa2s[j];
            }
            red2[jc * 64 + lane] = partial;
        }
        __syncthreads();                                 // B3: red2 ready

        // ---- C2: wave0 posts score-partials; all waves run P4 (hides RTT) ----
        if (wv == 0) {
            float s = 0.f;
            #pragma unroll
            for (int w2 = 0; w2 < 16; ++w2) s += red2[w2 * 64 + lane];
            sownl[lane] = s;
            atomicExch(&SXown[lane], s);
            asm volatile("s_waitcnt vmcnt(0)" ::: "memory");
            if (lane == 0) atomicExch(&FLGown[1], tgt);  // score flag
        }
        float g0 = 0.f, g1 = 0.f;
        #pragma unroll
        for (int kk = 0; kk < 6; ++kk) {                 // cached in LDS (96 KB)
            h8_t w  = wc[kk * 1024 + tid];
            h8_t hv = *(const h8_t*)(hgk + kk * 8);
            g0 = FDOT2(h2of(w, 0), h2of(hv, 0), g0);
            g1 = FDOT2(h2of(w, 1), h2of(hv, 1), g1);
            g0 = FDOT2(h2of(w, 2), h2of(hv, 2), g0);
            g1 = FDOT2(h2of(w, 3), h2of(hv, 3), g1);
        }
        #pragma unroll 5
        for (int kk = 6; kk < 16; ++kk) {                // streamed from L2 (160 KB)
            h8_t w  = W4[kk * 1024];
            h8_t hv = *(const h8_t*)(hgk + kk * 8);
            g0 = FDOT2(h2of(w, 0), h2of(hv, 0), g0);
            g1 = FDOT2(h2of(w, 1), h2of(hv, 1), g1);
            g0 = FDOT2(h2of(w, 2), h2of(hv, 2), g0);
            g1 = FDOT2(h2of(w, 3), h2of(hv, 3), g1);
        }
        g2[tid] = g0 + g1;
        if (tid == 0) {
            while (atomicAdd(&FLGpeer[1], 0u) < tgt) { __builtin_amdgcn_s_sleep(1); }
        }
        __syncthreads();                                 // B4: g2 ready + peer scores posted

        // ---- D+H fused (tid<128 = waves 0,1): redundant softmax + ytil,
        //      then gate finalize + own-slice state update + packed post ----
        if (tid < 128) {
            float sp = atomicAdd(&SXpeer[lane], 0.f);
            float s  = sownl[lane] + sp;                 // commutative pair sum
            float m = s;
            #pragma unroll
            for (int d = 32; d >= 1; d >>= 1) m = fmaxf(m, __shfl_xor(m, d));
            float e = __expf(s - m);
            float su = e;
            #pragma unroll
            for (int d = 32; d >= 1; d >>= 1) su += __shfl_xor(su, d);
            float a = e * __builtin_amdgcn_rcpf(su);
            if (wv == 0) attnw[lane] = a;
            float yp = a * encw[lane];
            #pragma unroll
            for (int d = 32; d >= 1; d >>= 1) yp += __shfl_xor(yp, d);
            const float ytil = yp + wfc_y * ys[step] + bfc0;

            float gi = g2[tid]       + g2[512 + tid] + ytil * wii + bsi;
            float gf = g2[128 + tid] + g2[640 + tid] + ytil * wif + bsf;
            float gg = g2[256 + tid] + g2[768 + tid] + ytil * wig + bsg;
            float go = g2[384 + tid] + g2[896 + tid] + ytil * wio + bso;
            const int ih = h1 * 128 + tid;
            float co = hc[256 + ih];
            float cn = fsig(gf) * co + fsig(gi) * ftanh(gg);
            float hn = fsig(go) * ftanh(cn);
            hc[ih] = hn; hc[256 + ih] = cn;
            hcf16[ih] = (_Float16)hn; hcf16[256 + ih] = (_Float16)cn;
            atomicExch(&HXown[tid], pack_hc(hn, cn));    // packed post
        }
        __syncthreads();                                 // B6: updated + posts drained
        if (tid == 0) atomicExch(&FLGown[0], tgt);       // state flag
    }

    // ---- final: read peer h for the epilogue ----
    if (tid == 0) {
        while (atomicAdd(&FLGpeer[0], 0u) < (unsigned)NSTEP) { __builtin_amdgcn_s_sleep(1); }
    }
    __syncthreads();
    if (tid < 128) {
        unsigned u = atomicAdd(&HXpeer[tid], 0u);
        _Float16 hv16 = __builtin_bit_cast(_Float16, (unsigned short)(u & 0xffffu));
        hc[(1 - h1) * 128 + tid] = (float)hv16;
    }
    __syncthreads();

    // ---- epilogue (h1 == 0 only): final ctx from attnw, then out ----
    if (h1 == 0) {
        if (tid < 256) {
            float cv = 0.f;
            #pragma unroll 8
            for (int t = 0; t < TENC; ++t)
                cv += attnw[t] * encb[t * 256 + tid];
            red1[tid] = cv;
        }
        __syncthreads();
        if (wv < 2) {
            float partial = 0.f;
            #pragma unroll
            for (int qq = 0; qq < 8; ++qq) {
                const int e2 = qq * 64 + lane;
                float v = (e2 < 256) ? hc[e2] : red1[e2 - 256];
                partial += v * Wff[wv * 512 + e2];
            }
            #pragma unroll
            for (int d = 32; d >= 1; d >>= 1) partial += __shfl_xor(partial, d);
            if (lane == 0) out[b * 2 + wv] = partial + bff[wv];
        }
    }
}

// ---------------------------------------------------------------------------
extern "C" void kernel_launch(void* const* d_in, const int* in_sizes, int n_in,
                              void* d_out, int out_size, void* d_ws, size_t ws_size,
                              hipStream_t stream) {
    const float* enc = (const float*)d_in[0];
    const float* yh  = (const float*)d_in[1];
    const float* Wa1 = (const float*)d_in[2];
    const float* ba1 = (const float*)d_in[3];
    const float* Wa2 = (const float*)d_in[4];
    // d_in[5] = b_a2 : softmax shift-invariant, unused
    const float* Wfc = (const float*)d_in[6];
    const float* bfc = (const float*)d_in[7];
    const float* Wih = (const float*)d_in[8];
    const float* Whh = (const float*)d_in[9];
    const float* bih = (const float*)d_in[10];
    const float* bhh = (const float*)d_in[11];
    const float* Wff = (const float*)d_in[12];
    const float* bff = (const float*)d_in[13];
    float* ws  = (float*)d_ws;
    float* out = (float*)d_out;

    hipLaunchKernelGGL(pack_weights, dim3(1792), dim3(256), 0, stream, Wa1, Whh, ws);
    hipLaunchKernelGGL(zero_flags, dim3(1), dim3(512), 0, stream, ws);
    hipLaunchKernelGGL(enc_proj_kernel, dim3(256), dim3(256), 0, stream, enc, ba1, ws);
    hipLaunchKernelGGL(decoder_main, dim3(256), dim3(1024), 0, stream,
                       enc, yh, Wa2, Wfc, bfc, Wih, bih, bhh, Wff, bff, ws, out);
}

// Round 15
// 398.824 us; speedup vs baseline: 1.3163x; 1.0241x over previous
//
#include <hip/hip_runtime.h>
#include <math.h>

// Problem constants
#define BATCH 128
#define TENC  64
#define NSTEP 63

// Workspace layout (FLOAT offsets)
#define OFF_WA1ET  0         // [256 k][256 j] f32 : W_a1[j][512+k]  (enc part, for enc_proj)
#define OFF_EPT    65536     // [128 b][256 j][64 t] f32
#define OFF_PKH    2162688   // fp16 region (half offsets within):
                             //   PK1n: [0,131072) = [hp<2][kc<4][seg<2][it<8][j7<128][m<8]
                             //         = Wa1[hp*128+j7][k]; owner=seg?1-hp:hp; idx256=kc*64+it*8+m;
                             //         k = idx256<128 ? owner*128+idx256 : 256+owner*128+(idx256-128)
                             //   PKG:  [131072,393216) = [h1<2][kk<16][kh<2][q'<512][m<8]
                             //         = Whh[q][k], q=(q'>>7)*256+h1*128+(q'&127), k=kh*128+kk*8+m
#define OFF_SX     2359296   // [128 b][2 half][64] f32    score-partial exchange
#define OFF_HX     2375680   // [128 b][2 half][128] u32   packed state exchange {h:f16 lo, c:f16 hi}
#define OFF_FLAGS  2408448   // [128 b][2 half][2] uint    (monotonic; 0=state, 1=scores)

// LDS flag ids
#define SF 0   // peer state in LDS     (2 posts/step, steps>=1)
#define AF 1   // red1 ready            (8 posts/step)
#define CF 2   // red2 ready            (8 posts/step)
#define GF 3   // g2 ready              (8 posts/step)

typedef __attribute__((ext_vector_type(8))) _Float16 h8_t;
typedef __attribute__((ext_vector_type(2))) _Float16 h2_t;

#if defined(__has_builtin)
#if __has_builtin(__builtin_amdgcn_fdot2)
#define FDOT2(a, b, c) __builtin_amdgcn_fdot2((a), (b), (c), false)
#endif
#endif
#ifndef FDOT2
#define FDOT2(a, b, c) ((c) + (float)(a)[0] * (float)(b)[0] + (float)(a)[1] * (float)(b)[1])
#endif

__device__ __forceinline__ h2_t h2of(h8_t v, int i) {
    h2_t r = {v[2 * i], v[2 * i + 1]};
    return r;
}
__device__ __forceinline__ float ftanh(float x) {
    x = fminf(15.f, fmaxf(-15.f, x));
    float e = __expf(2.f * x);
    return (e - 1.f) * __builtin_amdgcn_rcpf(e + 1.f);
}
__device__ __forceinline__ float fsig(float x) {
    return __builtin_amdgcn_rcpf(1.f + __expf(-x));
}
__device__ __forceinline__ unsigned pack_hc(float h, float c) {
    unsigned short hu = __builtin_bit_cast(unsigned short, (_Float16)h);
    unsigned short cu = __builtin_bit_cast(unsigned short, (_Float16)c);
    return (unsigned)hu | ((unsigned)cu << 16);
}
#define FENCE() asm volatile("" ::: "memory")
#define LGKM0() asm volatile("s_waitcnt lgkmcnt(0)" ::: "memory")

// ---------------------------------------------------------------------------
// Pre-kernel A: pack weights (fp16 stream-ordered) + WA1ET (f32)
// ---------------------------------------------------------------------------
__global__ void pack_weights(const float* __restrict__ Wa1,
                             const float* __restrict__ Whh,
                             float* __restrict__ ws) {
    int idx = blockIdx.x * blockDim.x + threadIdx.x;
    _Float16* PKH = (_Float16*)(ws + OFF_PKH);
    if (idx < 131072) {
        // PK1n decode: flat = ((((hp*4+kc)*2+seg)*8+it)*128 + j7)*8 + m
        int m = idx & 7, j7 = (idx >> 3) & 127, it = (idx >> 10) & 7;
        int seg = (idx >> 13) & 1, kc = (idx >> 14) & 3, hp = (idx >> 16) & 1;
        int owner = seg ? (1 - hp) : hp;
        int idx256 = kc * 64 + it * 8 + m;
        int k = (idx256 < 128) ? owner * 128 + idx256
                               : 256 + owner * 128 + (idx256 - 128);
        int j = hp * 128 + j7;
        PKH[idx] = (_Float16)Wa1[j * 768 + k];
    } else if (idx < 393216) {
        int n = idx - 131072;
        int m = n & 7, qp = (n >> 3) & 511, kh = (n >> 12) & 1, kk = (n >> 13) & 15, h1 = n >> 17;
        int q = ((qp >> 7) << 8) + h1 * 128 + (qp & 127);
        int k = kh * 128 + kk * 8 + m;
        PKH[131072 + n] = (_Float16)Whh[q * 256 + k];
    } else if (idx < 458752) {
        int n = idx - 393216;
        int k = n >> 8, j = n & 255;
        ws[OFF_WA1ET + n] = Wa1[j * 768 + 512 + k];
    }
}

// Pre-kernel A2: zero the exchange flags (every launch, before decoder)
__global__ void zero_flags(float* __restrict__ ws) {
    unsigned* f = (unsigned*)(ws + OFF_FLAGS);
    f[threadIdx.x] = 0u;   // 512 = [128][2][2]
}

// ---------------------------------------------------------------------------
// Pre-kernel B: EPT[b][j][t] = b_a1[j] + sum_k enc[b][t][k] * W_a1[j][512+k]
// ---------------------------------------------------------------------------
__global__ void enc_proj_kernel(const float* __restrict__ enc,
                                const float* __restrict__ ba1,
                                float* __restrict__ ws) {
    __shared__ float smem[8448];
    const int b  = blockIdx.x >> 1;
    const int th = blockIdx.x & 1;
    const int t0 = th * 32;
    const int tid = threadIdx.x;

    const float* encb = enc + (b * TENC + t0) * 256;
    for (int c = 0; c < 32; ++c) smem[c * 256 + tid] = encb[c * 256 + tid];
    __syncthreads();

    const int w = tid >> 6, l = tid & 63;
    float acc[8][4];
    #pragma unroll
    for (int a = 0; a < 8; ++a)
        #pragma unroll
        for (int c = 0; c < 4; ++c) acc[a][c] = 0.f;

    const float4* WT = (const float4*)(ws + OFF_WA1ET);
    for (int k = 0; k < 256; ++k) {
        float4 wv = WT[k * 64 + l];
        #pragma unroll
        for (int tt = 0; tt < 8; ++tt) {
            float e = smem[(w * 8 + tt) * 256 + k];
            acc[tt][0] += e * wv.x; acc[tt][1] += e * wv.y;
            acc[tt][2] += e * wv.z; acc[tt][3] += e * wv.w;
        }
    }
    float4 bb = ((const float4*)ba1)[l];
    __syncthreads();
    #pragma unroll
    for (int tt = 0; tt < 8; ++tt) {
        smem[(4 * l + 0) * 33 + w * 8 + tt] = acc[tt][0] + bb.x;
        smem[(4 * l + 1) * 33 + w * 8 + tt] = acc[tt][1] + bb.y;
        smem[(4 * l + 2) * 33 + w * 8 + tt] = acc[tt][2] + bb.z;
        smem[(4 * l + 3) * 33 + w * 8 + tt] = acc[tt][3] + bb.w;
    }
    __syncthreads();
    float* EPT = ws + OFF_EPT + b * 16384;
    for (int c = 0; c < 32; ++c) {
        int i = c * 256 + tid;
        int j = i >> 5, t5 = i & 31;
        EPT[j * 64 + t0 + t5] = smem[j * 33 + t5];
    }
}

// ---------------------------------------------------------------------------
// Main kernel: 256 WGs = 2 per batch; WG h1 owns state slice + j-half.
// WAVE-SPECIALIZED: waves 0-7 (tid<512) = attention chain (P1, scores,
// softmax, LSTM update); waves 8-15 = state ingest + full-k gate GEMV (P4).
// Intra-step sync via monotonic LDS flag counters; ONE __syncthreads/step.
// ---------------------------------------------------------------------------
__global__ __launch_bounds__(1024, 4) void decoder_main(
    const float* __restrict__ enc, const float* __restrict__ yhist,
    const float* __restrict__ Wa2,
    const float* __restrict__ Wfc, const float* __restrict__ bfc,
    const float* __restrict__ wih, const float* __restrict__ bih,
    const float* __restrict__ bhh,
    const float* __restrict__ Wff, const float* __restrict__ bff,
    float* __restrict__ ws, float* __restrict__ out) {

    __shared__ float hc[512];        // f32 state: h=[0,256), c=[256,512)
    __shared__ _Float16 hcf16[512] __attribute__((aligned(16)));
    __shared__ float red1[512];      // P1 partials [kc<4][j7<128]
    __shared__ float red2[512];      // score partials [jc<8][t<64]
    __shared__ float g2[512];        // COMPLETE gate dots [q'<512]
    __shared__ float attnw[64];
    __shared__ float encw[64];
    __shared__ float wa2s[128];
    __shared__ float ys[64];
    __shared__ unsigned fl[4];
    __shared__ h8_t  wc[7168] __attribute__((aligned(16)));  // 112 KB W_hh kk 0..7
    __shared__ float epl[8192];      // EPT own j-half : [128 j'][64 t]

    const int bid  = blockIdx.x;
    const int b    = bid & 127;
    const int h1   = bid >> 7;
    const int tid  = threadIdx.x;

    const _Float16* PKH = (const _Float16*)(ws + OFF_PKH);
    const float* EPTb = ws + OFF_EPT + b * 16384 + h1 * 8192;
    const float* encb = enc + b * 16384;

    // ---- prologue ----
    if (tid < 512) { hc[tid] = 0.f; hcf16[tid] = (_Float16)0.f; }
    if (tid < 128) wa2s[tid] = Wa2[h1 * 128 + tid];
    if (tid < NSTEP) ys[tid] = yhist[b * NSTEP + tid];
    if (tid < 4) fl[tid] = 0u;
    {   // encw partials into wc scratch (before wc is loaded)
        float* scr = (float*)wc;
        const int t = tid >> 4, cch = tid & 15;
        float p = 0.f;
        #pragma unroll
        for (int i = 0; i < 16; ++i)
            p += encb[t * 256 + cch * 16 + i] * Wfc[cch * 16 + i];
        scr[t * 16 + cch] = p;
    }
    __syncthreads();
    if (tid < 64) {
        float s = 0.f;
        #pragma unroll
        for (int c = 0; c < 16; ++c) s += ((float*)wc)[tid * 16 + c];
        encw[tid] = s;
    }
    __syncthreads();
    #pragma unroll
    for (int i = 0; i < 8; ++i) epl[i * 1024 + tid] = EPTb[i * 1024 + tid];
    const h8_t* PKGown = (const h8_t*)(PKH + 131072) + h1 * 16384;
    #pragma unroll
    for (int kk = 0; kk < 7; ++kk) wc[kk * 1024 + tid] = PKGown[kk * 1024 + tid];
    const float bfc0  = bfc[0];
    const float wfc_y = Wfc[256];
    float wii = 0.f, wif = 0.f, wig = 0.f, wio = 0.f;
    float bsi = 0.f, bsf = 0.f, bsg = 0.f, bso = 0.f;
    if (tid < 128) {
        const int q0 = h1 * 128 + tid;
        wii = wih[q0];       bsi = bih[q0]       + bhh[q0];
        wif = wih[256 + q0]; bsf = bih[256 + q0] + bhh[256 + q0];
        wig = wih[512 + q0]; bsg = bih[512 + q0] + bhh[512 + q0];
        wio = wih[768 + q0]; bso = bih[768 + q0] + bhh[768 + q0];
    }
    __syncthreads();

    // group-A P1 mapping (tid<512): j7 = tid&127, kc = tid>>7 (4 chunks of 64 k)
    const int j7 = tid & 127, kc = (tid >> 7) & 3;
    const h8_t* W1a = (const h8_t*)PKH + ((h1 * 4 + kc) * 2 + 0) * 1024 + j7;
    const h8_t* W1b = W1a + 1024;
    const _Float16* hb_own  = hcf16 + ((kc < 2) ? h1 * 128 + kc * 64
                                                : 256 + h1 * 128 + (kc - 2) * 64);
    const _Float16* hb_peer = hcf16 + ((kc < 2) ? (1 - h1) * 128 + kc * 64
                                                : 256 + (1 - h1) * 128 + (kc - 2) * 64);
    // group-B P4 mapping (tid>=512): q' = tid-512, full 256-k dot per thread
    const h8_t* W4 = PKGown + (tid - 512);

    // exchange buffers / flags
    float*    SXown  = ws + OFF_SX + (b * 2 + h1) * 64;
    float*    SXpeer = ws + OFF_SX + (b * 2 + (1 - h1)) * 64;
    unsigned* HXown  = (unsigned*)(ws + OFF_HX) + (b * 2 + h1) * 128;
    unsigned* HXpeer = (unsigned*)(ws + OFF_HX) + (b * 2 + (1 - h1)) * 128;
    unsigned* FLGown  = (unsigned*)(ws + OFF_FLAGS) + (b * 2 + h1) * 2;
    unsigned* FLGpeer = (unsigned*)(ws + OFF_FLAGS) + (b * 2 + (1 - h1)) * 2;

    for (int step = 0; step < NSTEP; ++step) {
        const unsigned tgt = (unsigned)(step + 1);
        if (tid < 512) {
            // ============== GROUP A: attention-critical chain ==============
            float a0 = 0.f, a1 = 0.f;
            // A1: own-k segment (64 KB stream; runs during peer-state ingest)
            #pragma unroll 4
            for (int it = 0; it < 8; ++it) {
                h8_t w  = W1a[it * 128];
                h8_t hv = *(const h8_t*)(hb_own + it * 8);
                a0 = FDOT2(h2of(w, 0), h2of(hv, 0), a0);
                a1 = FDOT2(h2of(w, 1), h2of(hv, 1), a1);
                a0 = FDOT2(h2of(w, 2), h2of(hv, 2), a0);
                a1 = FDOT2(h2of(w, 3), h2of(hv, 3), a1);
            }
            if (step) {
                while (atomicAdd(&fl[SF], 0u) < 2u * (unsigned)step)
                    __builtin_amdgcn_s_sleep(1);
                FENCE();
            }
            // A2: peer-k segment
            #pragma unroll 4
            for (int it = 0; it < 8; ++it) {
                h8_t w  = W1b[it * 128];
                h8_t hv = *(const h8_t*)(hb_peer + it * 8);
                a0 = FDOT2(h2of(w, 0), h2of(hv, 0), a0);
                a1 = FDOT2(h2of(w, 1), h2of(hv, 1), a1);
                a0 = FDOT2(h2of(w, 2), h2of(hv, 2), a0);
                a1 = FDOT2(h2of(w, 3), h2of(hv, 3), a1);
            }
            red1[kc * 128 + j7] = a0 + a1;
            LGKM0();
            if ((tid & 63) == 0) atomicAdd(&fl[AF], 1u);
            while (atomicAdd(&fl[AF], 0u) < 8u * tgt) __builtin_amdgcn_s_sleep(1);
            FENCE();
            // C: score partials over own j-half (z fused: 4-way red1 combine inline)
            {
                const int jc = tid >> 6, lane = tid & 63;
                float partial = 0.f;
                #pragma unroll
                for (int jj = 0; jj < 16; ++jj) {
                    const int j = jc * 16 + jj;
                    float zj = red1[j] + red1[128 + j] + red1[256 + j] + red1[384 + j];
                    float v = epl[j * 64 + lane] + zj;
                    partial += ftanh(v) * wa2s[j];
                }
                red2[jc * 64 + lane] = partial;
            }
            LGKM0();
            if ((tid & 63) == 0) atomicAdd(&fl[CF], 1u);
            // score-sum + post + softmax + gates + update: waves 0,1 only
            if (tid < 128) {
                const int lane = tid & 63;
                while (atomicAdd(&fl[CF], 0u) < 8u * tgt) __builtin_amdgcn_s_sleep(1);
                FENCE();
                float s = 0.f;
                #pragma unroll
                for (int jc2 = 0; jc2 < 8; ++jc2) s += red2[jc2 * 64 + lane];
                if (tid < 64) {
                    atomicExch(&SXown[lane], s);
                    asm volatile("s_waitcnt vmcnt(0)" ::: "memory");
                    if (lane == 0) atomicExch(&FLGown[1], tgt);
                }
                while (atomicAdd(&FLGpeer[1], 0u) < tgt) __builtin_amdgcn_s_sleep(1);
                FENCE();
                s += atomicAdd(&SXpeer[lane], 0.f);       // commutative pair sum
                float m = s;
                #pragma unroll
                for (int d = 32; d >= 1; d >>= 1) m = fmaxf(m, __shfl_xor(m, d));
                float e = __expf(s - m);
                float su = e;
                #pragma unroll
                for (int d = 32; d >= 1; d >>= 1) su += __shfl_xor(su, d);
                float a = e * __builtin_amdgcn_rcpf(su);
                if (tid < 64) attnw[lane] = a;
                float yp = a * encw[lane];
                #pragma unroll
                for (int d = 32; d >= 1; d >>= 1) yp += __shfl_xor(yp, d);
                const float ytil = yp + wfc_y * ys[step] + bfc0;
                while (atomicAdd(&fl[GF], 0u) < 8u * tgt) __builtin_amdgcn_s_sleep(1);
                FENCE();
                float gi = g2[tid]       + ytil * wii + bsi;
                float gf = g2[128 + tid] + ytil * wif + bsf;
                float gg = g2[256 + tid] + ytil * wig + bsg;
                float go = g2[384 + tid] + ytil * wio + bso;
                const int ih = h1 * 128 + tid;
                float co = hc[256 + ih];
                float cn = fsig(gf) * co + fsig(gi) * ftanh(gg);
                float hn = fsig(go) * ftanh(cn);
                hc[ih] = hn; hc[256 + ih] = cn;
                hcf16[ih] = (_Float16)hn; hcf16[256 + ih] = (_Float16)cn;
                atomicExch(&HXown[tid], pack_hc(hn, cn));
            }
        } else {
            // ============== GROUP B: state ingest + full-k gate GEMV =======
            const int u2 = tid - 512;
            if (step) {
                if (u2 < 128) {
                    while (atomicAdd(&FLGpeer[0], 0u) < (unsigned)step)
                        __builtin_amdgcn_s_sleep(1);
                    FENCE();
                    unsigned uu = atomicAdd(&HXpeer[u2], 0u);
                    _Float16 hv16 = __builtin_bit_cast(_Float16, (unsigned short)(uu & 0xffffu));
                    _Float16 cv16 = __builtin_bit_cast(_Float16, (unsigned short)(uu >> 16));
                    const int ih = (1 - h1) * 128 + u2;
                    hcf16[ih] = hv16; hcf16[256 + ih] = cv16;
                    hc[ih] = (float)hv16;                 // epilogue f32 copy
                    LGKM0();
                    if ((u2 & 63) == 0) atomicAdd(&fl[SF], 1u);
                }
                while (atomicAdd(&fl[SF], 0u) < 2u * (unsigned)step)
                    __builtin_amdgcn_s_sleep(1);
                FENCE();
            }
            // P4: complete gate dot over full h (256 k) for q' = u2
            float ga = 0.f, gb = 0.f;
            #pragma unroll
            for (int kk = 0; kk < 7; ++kk) {              // LDS-cached (112 KB)
                h8_t w0  = wc[kk * 1024 + u2];
                h8_t w1  = wc[kk * 1024 + 512 + u2];
                h8_t hv0 = *(const h8_t*)(hcf16 + kk * 8);
                h8_t hv1 = *(const h8_t*)(hcf16 + 128 + kk * 8);
                ga = FDOT2(h2of(w0, 0), h2of(hv0, 0), ga);
                gb = FDOT2(h2of(w1, 0), h2of(hv1, 0), gb);
                ga = FDOT2(h2of(w0, 1), h2of(hv0, 1), ga);
                gb = FDOT2(h2of(w1, 1), h2of(hv1, 1), gb);
                ga = FDOT2(h2of(w0, 2), h2of(hv0, 2), ga);
                gb = FDOT2(h2of(w1, 2), h2of(hv1, 2), gb);
                ga = FDOT2(h2of(w0, 3), h2of(hv0, 3), ga);
                gb = FDOT2(h2of(w1, 3), h2of(hv1, 3), gb);
            }
            #pragma unroll 3
            for (int kk = 7; kk < 16; ++kk) {             // streamed from L2 (144 KB)
                h8_t w0  = W4[kk * 1024];
                h8_t w1  = W4[kk * 1024 + 512];
                h8_t hv0 = *(const h8_t*)(hcf16 + kk * 8);
                h8_t hv1 = *(const h8_t*)(hcf16 + 128 + kk * 8);
                ga = FDOT2(h2of(w0, 0), h2of(hv0, 0), ga);
                gb = FDOT2(h2of(w1, 0), h2of(hv1, 0), gb);
                ga = FDOT2(h2of(w0, 1), h2of(hv0, 1), ga);
                gb = FDOT2(h2of(w1, 1), h2of(hv1, 1), gb);
                ga = FDOT2(h2of(w0, 2), h2of(hv0, 2), ga);
                gb = FDOT2(h2of(w1, 2), h2of(hv1, 2), gb);
                ga = FDOT2(h2of(w0, 3), h2of(hv0, 3), ga);
                gb = FDOT2(h2of(w1, 3), h2of(hv1, 3), gb);
            }
            g2[u2] = ga + gb;
            LGKM0();
            if ((u2 & 63) == 0) atomicAdd(&fl[GF], 1u);
        }
        __syncthreads();                                  // B6: step boundary
        if (tid == 0) atomicExch(&FLGown[0], tgt);        // state flag
    }

    // ---- final: read peer h for the epilogue ----
    if (tid == 0) {
        while (atomicAdd(&FLGpeer[0], 0u) < (unsigned)NSTEP) { __builtin_amdgcn_s_sleep(1); }
    }
    __syncthreads();
    if (tid < 128) {
        unsigned uu = atomicAdd(&HXpeer[tid], 0u);
        _Float16 hv16 = __builtin_bit_cast(_Float16, (unsigned short)(uu & 0xffffu));
        hc[(1 - h1) * 128 + tid] = (float)hv16;
    }
    __syncthreads();

    // ---- epilogue (h1 == 0 only): final ctx from attnw, then out ----
    if (h1 == 0) {
        if (tid < 256) {
            float cv = 0.f;
            #pragma unroll 8
            for (int t = 0; t < TENC; ++t)
                cv += attnw[t] * encb[t * 256 + tid];
            red1[tid] = cv;
        }
        __syncthreads();
        if (tid < 128) {
            const int wvv = tid >> 6, lane = tid & 63;
            float partial = 0.f;
            #pragma unroll
            for (int qq = 0; qq < 8; ++qq) {
                const int e2 = qq * 64 + lane;
                float v = (e2 < 256) ? hc[e2] : red1[e2 - 256];
                partial += v * Wff[wvv * 512 + e2];
            }
            #pragma unroll
            for (int d = 32; d >= 1; d >>= 1) partial += __shfl_xor(partial, d);
            if (lane == 0) out[b * 2 + wvv] = partial + bff[wvv];
        }
    }
}

// ---------------------------------------------------------------------------
extern "C" void kernel_launch(void* const* d_in, const int* in_sizes, int n_in,
                              void* d_out, int out_size, void* d_ws, size_t ws_size,
                              hipStream_t stream) {
    const float* enc = (const float*)d_in[0];
    const float* yh  = (const float*)d_in[1];
    const float* Wa1 = (const float*)d_in[2];
    const float* ba1 = (const float*)d_in[3];
    const float* Wa2 = (const float*)d_in[4];
    // d_in[5] = b_a2 : softmax shift-invariant, unused
    const float* Wfc = (const float*)d_in[6];
    const float* bfc = (const float*)d_in[7];
    const float* Wih = (const float*)d_in[8];
    const float* Whh = (const float*)d_in[9];
    const float* bih = (const float*)d_in[10];
    const float* bhh = (const float*)d_in[11];
    const float* Wff = (const float*)d_in[12];
    const float* bff = (const float*)d_in[13];
    float* ws  = (float*)d_ws;
    float* out = (float*)d_out;

    hipLaunchKernelGGL(pack_weights, dim3(1792), dim3(256), 0, stream, Wa1, Whh, ws);
    hipLaunchKernelGGL(zero_flags, dim3(1), dim3(512), 0, stream, ws);
    hipLaunchKernelGGL(enc_proj_kernel, dim3(256), dim3(256), 0, stream, enc, ba1, ws);
    hipLaunchKernelGGL(decoder_main, dim3(256), dim3(1024), 0, stream,
                       enc, yh, Wa2, Wfc, bfc, Wih, bih, bhh, Wff, bff, ws, out);
}